// Round 1
// baseline (728.607 us; speedup 1.0000x reference)
//
#include <hip/hip_runtime.h>

#define NBROWS 32768
#define ND 1024
#define NT 16
#define NC 1000
#define BM 128
#define BN 128
#define BK 32
#define MAX_RB (NBROWS / BM + NT)  // 272 worst-case row-blocks
#define NBN 8                      // 8*128 = 1024 >= 1000 cols

typedef short short8 __attribute__((ext_vector_type(8)));
typedef float f32x4 __attribute__((ext_vector_type(4)));

__device__ __forceinline__ unsigned f2bf(float f) {
  unsigned u = __float_as_uint(f);
  u += 0x7FFFu + ((u >> 16) & 1u);  // round-nearest-even
  return u >> 16;
}
__device__ __forceinline__ unsigned pk2(float a, float b) {
  return f2bf(a) | (f2bf(b) << 16);
}
__device__ __forceinline__ int swz(int row) {
  return (row & 3) ^ ((row >> 2) & 3);
}

// meta layout (ints): [0..15] counts, [16..32] offsets, [33..49] cbofs, [50..65] cursor
__global__ void trix_init(int* meta) {
  int i = threadIdx.x;
  if (i < 16) meta[i] = 0;
}

__global__ __launch_bounds__(256) void trix_scores(
    const float* __restrict__ x, const float* __restrict__ sigs_raw,
    int* __restrict__ tidx, float* __restrict__ out_idx, int* __restrict__ meta) {
  __shared__ signed char s_lds[NT * ND];
  int tid = threadIdx.x;
  for (int i = tid; i < NT * ND; i += 256) {
    float s = sigs_raw[i];
    s_lds[i] = (s > 0.3f) ? 1 : ((s < -0.3f) ? -1 : 0);
  }
  __syncthreads();
  int lane = tid & 63;
  int row = blockIdx.x * 4 + (tid >> 6);
  const float* xr = x + (size_t)row * ND;
  double acc[NT];
#pragma unroll
  for (int t = 0; t < NT; t++) acc[t] = 0.0;
#pragma unroll
  for (int c = 0; c < 4; c++) {
    int d0 = c * 256 + lane * 4;
    float4 v = *(const float4*)(xr + d0);
    double dv0 = v.x, dv1 = v.y, dv2 = v.z, dv3 = v.w;
#pragma unroll
    for (int t = 0; t < NT; t++) {
      int sv = *(const int*)(s_lds + t * ND + d0);
      acc[t] = fma((double)((sv << 24) >> 24), dv0, acc[t]);
      acc[t] = fma((double)((sv << 16) >> 24), dv1, acc[t]);
      acc[t] = fma((double)((sv << 8) >> 24), dv2, acc[t]);
      acc[t] = fma((double)(sv >> 24), dv3, acc[t]);
    }
  }
#pragma unroll
  for (int t = 0; t < NT; t++) {
    double v = acc[t];
#pragma unroll
    for (int o = 32; o > 0; o >>= 1) v += __shfl_down(v, o);
    acc[t] = v;
  }
  if (lane == 0) {
    double best = acc[0];
    int bt = 0;
#pragma unroll
    for (int t = 1; t < NT; t++)
      if (acc[t] > best) { best = acc[t]; bt = t; }  // strict > keeps first on tie, matches jnp.argmax
    tidx[row] = bt;
    out_idx[row] = (float)bt;
    atomicAdd(&meta[bt], 1);
  }
}

__global__ void trix_prefix(int* meta) {
  if (threadIdx.x == 0) {
    int off = 0, cb = 0;
    for (int t = 0; t < NT; t++) {
      meta[16 + t] = off;
      meta[50 + t] = off;
      meta[33 + t] = cb;
      off += meta[t];
      cb += (meta[t] + BM - 1) / BM;
    }
    meta[32] = off;
    meta[49] = cb;
  }
}

__global__ __launch_bounds__(256) void trix_scatter(
    const int* __restrict__ tidx, int* __restrict__ meta, int* __restrict__ rowlist) {
  int row = blockIdx.x * 256 + threadIdx.x;
  int t = tidx[row];
  int pos = atomicAdd(&meta[50 + t], 1);
  rowlist[pos] = row;
}

__global__ __launch_bounds__(256) void trix_gemm(
    const float* __restrict__ x, const float* __restrict__ W,
    const float* __restrict__ bias, const int* __restrict__ meta,
    const int* __restrict__ rowlist, float* __restrict__ out) {
  __shared__ __align__(16) unsigned char aT[BM * 64];  // 128 rows x 32 bf16 (64B), XOR-swizzled 16B slots
  __shared__ __align__(16) unsigned char bT[BN * 64];
  __shared__ int rl[BM];
  int nb = blockIdx.x, rb = blockIdx.y;
  if (rb >= meta[49]) return;
  int t = 0;
  while (t < NT - 1 && rb >= meta[34 + t]) t++;
  int row0 = meta[16 + t] + (rb - meta[33 + t]) * BM;
  int cnt = meta[17 + t] - row0;
  if (cnt > BM) cnt = BM;
  int tid = threadIdx.x;
  if (tid < BM) rl[tid] = rowlist[(tid < cnt) ? (row0 + tid) : row0];
  __syncthreads();

  int half = tid & 1, rloc = tid >> 1;
  const float* xp = x + (size_t)rl[rloc] * ND + half * 16;
  int wn = nb * BN + rloc;
  if (wn > NC - 1) wn = NC - 1;
  const float* wp = W + ((size_t)t * NC + wn) * ND + half * 16;
  int sw = swz(rloc);
  unsigned char* aw0 = aT + rloc * 64 + (((half * 2 + 0) ^ sw) << 4);
  unsigned char* aw1 = aT + rloc * 64 + (((half * 2 + 1) ^ sw) << 4);
  unsigned char* bw0 = bT + rloc * 64 + (((half * 2 + 0) ^ sw) << 4);
  unsigned char* bw1 = bT + rloc * 64 + (((half * 2 + 1) ^ sw) << 4);

  int lane = tid & 63, wv = tid >> 6;
  int wr = wv >> 1, wc = wv & 1;
  int rsel = lane & 15, slot = lane >> 4;
  f32x4 acc[4][4] = {};

  for (int k0 = 0; k0 < ND; k0 += BK) {
    const float* xk = xp + k0;
    const float* wk = wp + k0;
    float4 a0 = *(const float4*)(xk);
    float4 a1 = *(const float4*)(xk + 4);
    float4 a2 = *(const float4*)(xk + 8);
    float4 a3 = *(const float4*)(xk + 12);
    float4 b0 = *(const float4*)(wk);
    float4 b1 = *(const float4*)(wk + 4);
    float4 b2 = *(const float4*)(wk + 8);
    float4 b3 = *(const float4*)(wk + 12);
    uint4 pa0 = make_uint4(pk2(a0.x, a0.y), pk2(a0.z, a0.w), pk2(a1.x, a1.y), pk2(a1.z, a1.w));
    uint4 pa1 = make_uint4(pk2(a2.x, a2.y), pk2(a2.z, a2.w), pk2(a3.x, a3.y), pk2(a3.z, a3.w));
    uint4 pb0 = make_uint4(pk2(b0.x, b0.y), pk2(b0.z, b0.w), pk2(b1.x, b1.y), pk2(b1.z, b1.w));
    uint4 pb1 = make_uint4(pk2(b2.x, b2.y), pk2(b2.z, b2.w), pk2(b3.x, b3.y), pk2(b3.z, b3.w));
    *(uint4*)aw0 = pa0;
    *(uint4*)aw1 = pa1;
    *(uint4*)bw0 = pb0;
    *(uint4*)bw1 = pb1;
    __syncthreads();
    short8 af[4], bf[4];
#pragma unroll
    for (int i = 0; i < 4; i++) {
      int ar = wr * 64 + i * 16 + rsel;
      af[i] = *(const short8*)(aT + ar * 64 + ((slot ^ swz(ar)) << 4));
      int br = wc * 64 + i * 16 + rsel;
      bf[i] = *(const short8*)(bT + br * 64 + ((slot ^ swz(br)) << 4));
    }
#pragma unroll
    for (int mi = 0; mi < 4; mi++)
#pragma unroll
      for (int ni = 0; ni < 4; ni++)
        acc[mi][ni] = __builtin_amdgcn_mfma_f32_16x16x32_bf16(af[mi], bf[ni], acc[mi][ni], 0, 0, 0);
    __syncthreads();
  }

#pragma unroll
  for (int mi = 0; mi < 4; mi++) {
#pragma unroll
    for (int r = 0; r < 4; r++) {
      int rloc2 = wr * 64 + mi * 16 + slot * 4 + r;  // C/D: col=lane&15, row=(lane>>4)*4+reg
      if (rloc2 < cnt) {
        size_t obase = (size_t)rl[rloc2] * NC;
#pragma unroll
        for (int ni = 0; ni < 4; ni++) {
          int col = nb * BN + wc * 64 + ni * 16 + rsel;
          if (col < NC) out[obase + col] = acc[mi][ni][r] + bias[t * NC + col];
        }
      }
    }
  }
}

extern "C" void kernel_launch(void* const* d_in, const int* in_sizes, int n_in,
                              void* d_out, int out_size, void* d_ws, size_t ws_size,
                              hipStream_t stream) {
  const float* x = (const float*)d_in[0];
  const float* sigs = (const float*)d_in[1];
  const float* W = (const float*)d_in[2];
  const float* bias = (const float*)d_in[3];
  float* out = (float*)d_out;
  int* tidx = (int*)d_ws;
  int* rowlist = tidx + NBROWS;
  int* meta = rowlist + NBROWS;

  trix_init<<<1, 64, 0, stream>>>(meta);
  trix_scores<<<NBROWS / 4, 256, 0, stream>>>(x, sigs, tidx, out + (size_t)NBROWS * NC, meta);
  trix_prefix<<<1, 64, 0, stream>>>(meta);
  trix_scatter<<<NBROWS / 256, 256, 0, stream>>>(tidx, meta, rowlist);
  trix_gemm<<<dim3(NBN, MAX_RB), 256, 0, stream>>>(x, W, bias, meta, rowlist, out);
}

// Round 2
// 638.187 us; speedup vs baseline: 1.1417x; 1.1417x over previous
//
#include <hip/hip_runtime.h>

#define NBROWS 32768
#define ND 1024
#define NT 16
#define NC 1000
#define BM 128
#define BN 128
#define MAX_RB (NBROWS / BM + NT)  // 272 worst-case row-blocks
#define NBN 8                      // 8*128 = 1024 >= 1000 cols

typedef short short8 __attribute__((ext_vector_type(8)));
typedef float f32x4 __attribute__((ext_vector_type(4)));
typedef unsigned short ushort_t;

typedef __attribute__((address_space(1))) const unsigned int* gas_t;
typedef __attribute__((address_space(3))) unsigned int* las_t;

__device__ __forceinline__ void async_copy16(const void* g, void* l) {
  __builtin_amdgcn_global_load_lds((gas_t)g, (las_t)l, 16, 0, 0);
}

__device__ __forceinline__ unsigned f2bf(float f) {
  unsigned u = __float_as_uint(f);
  u += 0x7FFFu + ((u >> 16) & 1u);  // round-nearest-even
  return u >> 16;
}
__device__ __forceinline__ unsigned pk2(float a, float b) {
  return f2bf(a) | (f2bf(b) << 16);
}
__device__ __forceinline__ int swz(int row) {
  return (row & 3) ^ ((row >> 2) & 3);
}

// meta layout (ints): [0..15] counts, [16..32] offsets, [33..49] cbofs, [50..65] cursor
__global__ void trix_init(int* meta) {
  int i = threadIdx.x;
  if (i < 16) meta[i] = 0;
}

// 512 threads = 8 rows/block. Pure f32: per elem per tile {bfe,cvt,fmac};
// butterfly f32 reduce; also emits x as bf16 for the GEMM (fast path).
__global__ __launch_bounds__(512) void trix_scores(
    const float* __restrict__ x, const float* __restrict__ sigs_raw,
    int* __restrict__ tidx, float* __restrict__ out_idx, int* __restrict__ meta,
    ushort_t* __restrict__ xbf) {
  __shared__ signed char s_lds[NT * ND];
  int tid = threadIdx.x;
  for (int i = tid; i < NT * ND; i += 512) {
    float s = sigs_raw[i];
    s_lds[i] = (s > 0.3f) ? 1 : ((s < -0.3f) ? -1 : 0);
  }
  __syncthreads();
  int lane = tid & 63;
  int row = blockIdx.x * 8 + (tid >> 6);
  const float* xr = x + (size_t)row * ND + lane * 16;
  float4 v0 = *(const float4*)(xr);
  float4 v1 = *(const float4*)(xr + 4);
  float4 v2 = *(const float4*)(xr + 8);
  float4 v3 = *(const float4*)(xr + 12);
  float xv[16] = {v0.x, v0.y, v0.z, v0.w, v1.x, v1.y, v1.z, v1.w,
                  v2.x, v2.y, v2.z, v2.w, v3.x, v3.y, v3.z, v3.w};
  if (xbf) {
    uint4 p0 = make_uint4(pk2(v0.x, v0.y), pk2(v0.z, v0.w), pk2(v1.x, v1.y), pk2(v1.z, v1.w));
    uint4 p1 = make_uint4(pk2(v2.x, v2.y), pk2(v2.z, v2.w), pk2(v3.x, v3.y), pk2(v3.z, v3.w));
    ushort_t* xo = xbf + (size_t)row * ND + lane * 16;
    *(uint4*)(xo) = p0;
    *(uint4*)(xo + 8) = p1;
  }
  float best = 0.0f;
  int bt = 0;
#pragma unroll
  for (int t = 0; t < NT; t++) {
    int4 sc = *(const int4*)(s_lds + t * ND + lane * 16);
    int wa[4] = {sc.x, sc.y, sc.z, sc.w};
    float p = 0.0f;
#pragma unroll
    for (int wi = 0; wi < 4; wi++)
#pragma unroll
      for (int bi = 0; bi < 4; bi++)
        p = fmaf((float)(signed char)(wa[wi] >> (8 * bi)), xv[wi * 4 + bi], p);
#pragma unroll
    for (int o = 32; o > 0; o >>= 1) p += __shfl_xor(p, o);
    if (t == 0 || p > best) { best = p; bt = t; }  // strict >: first index on tie (jnp.argmax)
  }
  if (lane == 0) {
    tidx[row] = bt;
    out_idx[row] = (float)bt;
    atomicAdd(&meta[bt], 1);
  }
}

__global__ void trix_prefix(int* meta) {
  if (threadIdx.x == 0) {
    int off = 0, cb = 0;
    for (int t = 0; t < NT; t++) {
      meta[16 + t] = off;
      meta[50 + t] = off;
      meta[33 + t] = cb;
      off += meta[t];
      cb += (meta[t] + BM - 1) / BM;
    }
    meta[32] = off;
    meta[49] = cb;
  }
}

__global__ __launch_bounds__(256) void trix_scatter(
    const int* __restrict__ tidx, int* __restrict__ meta, int* __restrict__ rowlist) {
  int row = blockIdx.x * 256 + threadIdx.x;
  int t = tidx[row];
  int pos = atomicAdd(&meta[50 + t], 1);
  rowlist[pos] = row;
}

// W f32 [16][1000][1024] -> bf16 [16][1024][1024], cols 1000..1023 zeroed.
__global__ __launch_bounds__(256) void w_conv(const float* __restrict__ W,
                                              ushort_t* __restrict__ wbf) {
  size_t e = ((size_t)blockIdx.x * 256 + threadIdx.x) * 8;
  int t = (int)(e >> 20);
  int rem = (int)(e & 1048575);
  int col = rem >> 10, k = rem & 1023;
  uint4 o;
  if (col < NC) {
    const float* src = W + ((size_t)t * NC + col) * ND + k;
    float4 a = *(const float4*)src;
    float4 b = *(const float4*)(src + 4);
    o = make_uint4(pk2(a.x, a.y), pk2(a.z, a.w), pk2(b.x, b.y), pk2(b.z, b.w));
  } else {
    o = make_uint4(0, 0, 0, 0);
  }
  *(uint4*)(wbf + e) = o;
}

// m97-structure GEMM: linear LDS [128][32] bf16, global_load_lds width-16,
// 8 ds_read_b128 + 16 MFMA per k-step, 2 barriers.
__global__ __launch_bounds__(256) void trix_gemm_bf16(
    const ushort_t* __restrict__ xbf, const ushort_t* __restrict__ wbf,
    const float* __restrict__ bias, const int* __restrict__ meta,
    const int* __restrict__ rowlist, float* __restrict__ out) {
  __shared__ __align__(16) ushort_t A_lds[BM * 32];
  __shared__ __align__(16) ushort_t B_lds[BN * 32];
  __shared__ int rl[BM];
  int nb = blockIdx.x, rb = blockIdx.y;
  if (rb >= meta[49]) return;
  int t = 0;
  while (t < NT - 1 && rb >= meta[34 + t]) t++;
  int row0 = meta[16 + t] + (rb - meta[33 + t]) * BM;
  int cnt = meta[17 + t] - row0;
  if (cnt > BM) cnt = BM;
  int tid = threadIdx.x;
  if (tid < BM) rl[tid] = rowlist[(tid < cnt) ? (row0 + tid) : row0];
  __syncthreads();

  // staging: chunk c = row*4 + q (16B each); c0 = tid (rows 0..63), c1 = tid+256 (rows 64..127)
  int cr = tid >> 2, cq = tid & 3;
  const ushort_t* ga0 = xbf + (size_t)rl[cr] * ND + cq * 8;
  const ushort_t* ga1 = xbf + (size_t)rl[64 + cr] * ND + cq * 8;
  const ushort_t* gb0 = wbf + ((size_t)t << 20) + (size_t)(nb * BN + cr) * ND + cq * 8;
  const ushort_t* gb1 = wbf + ((size_t)t << 20) + (size_t)(nb * BN + 64 + cr) * ND + cq * 8;
  ushort_t* la0 = A_lds + tid * 8;
  ushort_t* la1 = A_lds + 2048 + tid * 8;
  ushort_t* lb0 = B_lds + tid * 8;
  ushort_t* lb1 = B_lds + 2048 + tid * 8;

  int lane = tid & 63, wv = tid >> 6;
  int wr = wv >> 1, wc = wv & 1;
  int rsel = lane & 15, slot = lane >> 4;
  f32x4 acc[4][4] = {};

  for (int k0 = 0; k0 < ND; k0 += 32) {
    async_copy16(ga0 + k0, la0);
    async_copy16(ga1 + k0, la1);
    async_copy16(gb0 + k0, lb0);
    async_copy16(gb1 + k0, lb1);
    __syncthreads();
    short8 af[4], bfr[4];
#pragma unroll
    for (int i = 0; i < 4; i++) {
      af[i] = *(const short8*)(A_lds + (wr * 64 + i * 16 + rsel) * 32 + slot * 8);
      bfr[i] = *(const short8*)(B_lds + (wc * 64 + i * 16 + rsel) * 32 + slot * 8);
    }
#pragma unroll
    for (int mi = 0; mi < 4; mi++)
#pragma unroll
      for (int ni = 0; ni < 4; ni++)
        acc[mi][ni] = __builtin_amdgcn_mfma_f32_16x16x32_bf16(af[mi], bfr[ni], acc[mi][ni], 0, 0, 0);
    __syncthreads();
  }

#pragma unroll
  for (int mi = 0; mi < 4; mi++) {
#pragma unroll
    for (int r = 0; r < 4; r++) {
      int rloc2 = wr * 64 + mi * 16 + slot * 4 + r;  // C/D: col=lane&15, row=(lane>>4)*4+reg
      if (rloc2 < cnt) {
        size_t obase = (size_t)rl[rloc2] * NC;
#pragma unroll
        for (int ni = 0; ni < 4; ni++) {
          int col = nb * BN + wc * 64 + ni * 16 + rsel;
          if (col < NC) out[obase + col] = acc[mi][ni][r] + bias[t * NC + col];
        }
      }
    }
  }
}

// Fallback GEMM (round-1, f32 inputs with in-loop repack) if ws is too small.
__global__ __launch_bounds__(256) void trix_gemm_fb(
    const float* __restrict__ x, const float* __restrict__ W,
    const float* __restrict__ bias, const int* __restrict__ meta,
    const int* __restrict__ rowlist, float* __restrict__ out) {
  __shared__ __align__(16) unsigned char aT[BM * 64];
  __shared__ __align__(16) unsigned char bT[BN * 64];
  __shared__ int rl[BM];
  int nb = blockIdx.x, rb = blockIdx.y;
  if (rb >= meta[49]) return;
  int t = 0;
  while (t < NT - 1 && rb >= meta[34 + t]) t++;
  int row0 = meta[16 + t] + (rb - meta[33 + t]) * BM;
  int cnt = meta[17 + t] - row0;
  if (cnt > BM) cnt = BM;
  int tid = threadIdx.x;
  if (tid < BM) rl[tid] = rowlist[(tid < cnt) ? (row0 + tid) : row0];
  __syncthreads();
  int half = tid & 1, rloc = tid >> 1;
  const float* xp = x + (size_t)rl[rloc] * ND + half * 16;
  int wn = nb * BN + rloc;
  if (wn > NC - 1) wn = NC - 1;
  const float* wp = W + ((size_t)t * NC + wn) * ND + half * 16;
  int sw = swz(rloc);
  unsigned char* aw0 = aT + rloc * 64 + (((half * 2 + 0) ^ sw) << 4);
  unsigned char* aw1 = aT + rloc * 64 + (((half * 2 + 1) ^ sw) << 4);
  unsigned char* bw0 = bT + rloc * 64 + (((half * 2 + 0) ^ sw) << 4);
  unsigned char* bw1 = bT + rloc * 64 + (((half * 2 + 1) ^ sw) << 4);
  int lane = tid & 63, wv = tid >> 6;
  int wr = wv >> 1, wc = wv & 1;
  int rsel = lane & 15, slot = lane >> 4;
  f32x4 acc[4][4] = {};
  for (int k0 = 0; k0 < ND; k0 += 32) {
    const float* xk = xp + k0;
    const float* wk = wp + k0;
    float4 a0 = *(const float4*)(xk);
    float4 a1 = *(const float4*)(xk + 4);
    float4 a2 = *(const float4*)(xk + 8);
    float4 a3 = *(const float4*)(xk + 12);
    float4 b0 = *(const float4*)(wk);
    float4 b1 = *(const float4*)(wk + 4);
    float4 b2 = *(const float4*)(wk + 8);
    float4 b3 = *(const float4*)(wk + 12);
    *(uint4*)aw0 = make_uint4(pk2(a0.x, a0.y), pk2(a0.z, a0.w), pk2(a1.x, a1.y), pk2(a1.z, a1.w));
    *(uint4*)aw1 = make_uint4(pk2(a2.x, a2.y), pk2(a2.z, a2.w), pk2(a3.x, a3.y), pk2(a3.z, a3.w));
    *(uint4*)bw0 = make_uint4(pk2(b0.x, b0.y), pk2(b0.z, b0.w), pk2(b1.x, b1.y), pk2(b1.z, b1.w));
    *(uint4*)bw1 = make_uint4(pk2(b2.x, b2.y), pk2(b2.z, b2.w), pk2(b3.x, b3.y), pk2(b3.z, b3.w));
    __syncthreads();
    short8 af[4], bfr[4];
#pragma unroll
    for (int i = 0; i < 4; i++) {
      int ar = wr * 64 + i * 16 + rsel;
      af[i] = *(const short8*)(aT + ar * 64 + ((slot ^ swz(ar)) << 4));
      int br = wc * 64 + i * 16 + rsel;
      bfr[i] = *(const short8*)(bT + br * 64 + ((slot ^ swz(br)) << 4));
    }
#pragma unroll
    for (int mi = 0; mi < 4; mi++)
#pragma unroll
      for (int ni = 0; ni < 4; ni++)
        acc[mi][ni] = __builtin_amdgcn_mfma_f32_16x16x32_bf16(af[mi], bfr[ni], acc[mi][ni], 0, 0, 0);
    __syncthreads();
  }
#pragma unroll
  for (int mi = 0; mi < 4; mi++) {
#pragma unroll
    for (int r = 0; r < 4; r++) {
      int rloc2 = wr * 64 + mi * 16 + slot * 4 + r;
      if (rloc2 < cnt) {
        size_t obase = (size_t)rl[rloc2] * NC;
#pragma unroll
        for (int ni = 0; ni < 4; ni++) {
          int col = nb * BN + wc * 64 + ni * 16 + rsel;
          if (col < NC) out[obase + col] = acc[mi][ni][r] + bias[t * NC + col];
        }
      }
    }
  }
}

extern "C" void kernel_launch(void* const* d_in, const int* in_sizes, int n_in,
                              void* d_out, int out_size, void* d_ws, size_t ws_size,
                              hipStream_t stream) {
  const float* x = (const float*)d_in[0];
  const float* sigs = (const float*)d_in[1];
  const float* W = (const float*)d_in[2];
  const float* bias = (const float*)d_in[3];
  float* out = (float*)d_out;

  const size_t XBF = (size_t)NBROWS * ND * 2;    // 67,108,864
  const size_t WBF = (size_t)NT * 1024 * ND * 2; // 33,554,432
  bool fast = ws_size >= XBF + WBF + (1 << 20);

  char* wsb = (char*)d_ws;
  ushort_t* xbf = nullptr;
  ushort_t* wbf = nullptr;
  int* tidx;
  if (fast) {
    xbf = (ushort_t*)wsb;
    wbf = (ushort_t*)(wsb + XBF);
    tidx = (int*)(wsb + XBF + WBF);
  } else {
    tidx = (int*)wsb;
  }
  int* rowlist = tidx + NBROWS;
  int* meta = rowlist + NBROWS;

  trix_init<<<1, 64, 0, stream>>>(meta);
  trix_scores<<<NBROWS / 8, 512, 0, stream>>>(x, sigs, tidx, out + (size_t)NBROWS * NC, meta, xbf);
  trix_prefix<<<1, 64, 0, stream>>>(meta);
  trix_scatter<<<NBROWS / 256, 256, 0, stream>>>(tidx, meta, rowlist);
  if (fast) {
    w_conv<<<(NT * 1024 * ND / 8) / 256, 256, 0, stream>>>(W, wbf);
    trix_gemm_bf16<<<dim3(NBN, MAX_RB), 256, 0, stream>>>(xbf, wbf, bias, meta, rowlist, out);
  } else {
    trix_gemm_fb<<<dim3(NBN, MAX_RB), 256, 0, stream>>>(x, W, bias, meta, rowlist, out);
  }
}

// Round 3
// 230.641 us; speedup vs baseline: 3.1590x; 2.7670x over previous
//
#include <hip/hip_runtime.h>

#define NBROWS 32768
#define ND 1024
#define NT 16
#define NC 1000
#define BM 128
#define BN 128
#define MAX_RB (NBROWS / BM + NT)  // 272 worst-case row-blocks
#define NBN 8                      // 8*128 = 1024 >= 1000 cols
#define NHB (NBROWS / 256)         // 128 histogram blocks

typedef short short8 __attribute__((ext_vector_type(8)));
typedef float f32x4 __attribute__((ext_vector_type(4)));
typedef unsigned short ushort_t;

typedef __attribute__((address_space(1))) const unsigned int* gas_t;
typedef __attribute__((address_space(3))) unsigned int* las_t;

__device__ __forceinline__ void async_copy16(const void* g, void* l) {
  __builtin_amdgcn_global_load_lds((gas_t)g, (las_t)l, 16, 0, 0);
}

__device__ __forceinline__ unsigned f2bf(float f) {
  unsigned u = __float_as_uint(f);
  u += 0x7FFFu + ((u >> 16) & 1u);  // round-nearest-even
  return u >> 16;
}
__device__ __forceinline__ unsigned pk2(float a, float b) {
  return f2bf(a) | (f2bf(b) << 16);
}
__device__ __forceinline__ int swz(int row) {
  return (row & 3) ^ ((row >> 2) & 3);
}

// 512 threads = 8 rows/block, one row per wave. Pure f32 fma chain +
// butterfly reduce. NO global atomics. Also emits x as bf16 (fast path).
__global__ __launch_bounds__(512) void trix_scores(
    const float* __restrict__ x, const float* __restrict__ sigs_raw,
    int* __restrict__ tidx, float* __restrict__ out_idx,
    ushort_t* __restrict__ xbf) {
  __shared__ signed char s_lds[NT * ND];
  int tid = threadIdx.x;
  for (int i = tid; i < NT * ND; i += 512) {
    float s = sigs_raw[i];
    s_lds[i] = (s > 0.3f) ? 1 : ((s < -0.3f) ? -1 : 0);
  }
  __syncthreads();
  int lane = tid & 63;
  int row = blockIdx.x * 8 + (tid >> 6);
  const float* xr = x + (size_t)row * ND + lane * 16;
  float4 v0 = *(const float4*)(xr);
  float4 v1 = *(const float4*)(xr + 4);
  float4 v2 = *(const float4*)(xr + 8);
  float4 v3 = *(const float4*)(xr + 12);
  float xv[16] = {v0.x, v0.y, v0.z, v0.w, v1.x, v1.y, v1.z, v1.w,
                  v2.x, v2.y, v2.z, v2.w, v3.x, v3.y, v3.z, v3.w};
  if (xbf) {
    uint4 p0 = make_uint4(pk2(v0.x, v0.y), pk2(v0.z, v0.w), pk2(v1.x, v1.y), pk2(v1.z, v1.w));
    uint4 p1 = make_uint4(pk2(v2.x, v2.y), pk2(v2.z, v2.w), pk2(v3.x, v3.y), pk2(v3.z, v3.w));
    ushort_t* xo = xbf + (size_t)row * ND + lane * 16;
    *(uint4*)(xo) = p0;
    *(uint4*)(xo + 8) = p1;
  }
  float best = 0.0f;
  int bt = 0;
#pragma unroll
  for (int t = 0; t < NT; t++) {
    int4 sc = *(const int4*)(s_lds + t * ND + lane * 16);
    int wa[4] = {sc.x, sc.y, sc.z, sc.w};
    float p = 0.0f;
#pragma unroll
    for (int wi = 0; wi < 4; wi++)
#pragma unroll
      for (int bi = 0; bi < 4; bi++)
        p = fmaf((float)(signed char)(wa[wi] >> (8 * bi)), xv[wi * 4 + bi], p);
#pragma unroll
    for (int o = 32; o > 0; o >>= 1) p += __shfl_xor(p, o);
    if (t == 0 || p > best) { best = p; bt = t; }  // strict >: first index on tie (jnp.argmax)
  }
  if (lane == 0) {
    tidx[row] = bt;
    out_idx[row] = (float)bt;
  }
}

// Per-block 16-bin histogram via LDS atomics only.
__global__ __launch_bounds__(256) void trix_hist(const int* __restrict__ tidx,
                                                 int* __restrict__ blkhist) {
  __shared__ int h[NT];
  int tid = threadIdx.x;
  if (tid < NT) h[tid] = 0;
  __syncthreads();
  int t = tidx[blockIdx.x * 256 + tid];
  atomicAdd(&h[t], 1);
  __syncthreads();
  if (tid < NT) blkhist[blockIdx.x * NT + tid] = h[tid];
}

// meta layout (ints): [0..15] counts, [16..32] offsets, [33..49] cbofs (49=total cb)
__global__ __launch_bounds__(256) void trix_prefix(const int* __restrict__ blkhist,
                                                   int* __restrict__ blkbase,
                                                   int* __restrict__ meta) {
  __shared__ int part[NT][16];
  int tid = threadIdx.x;
  int t = tid >> 4, g = tid & 15;
  int s = 0;
  for (int b = g; b < NHB; b += 16) s += blkhist[b * NT + t];
  part[t][g] = s;
  __syncthreads();
  if (tid == 0) {
    int off = 0, cb = 0;
    for (int tt = 0; tt < NT; tt++) {
      int c = 0;
#pragma unroll
      for (int gg = 0; gg < 16; gg++) c += part[tt][gg];
      meta[tt] = c;
      meta[16 + tt] = off;
      meta[33 + tt] = cb;
      off += c;
      cb += (c + BM - 1) / BM;
    }
    meta[32] = off;
    meta[49] = cb;
  }
  __syncthreads();
  if (tid < NT) {
    int run = meta[16 + tid];
    for (int b = 0; b < NHB; b++) {
      blkbase[b * NT + tid] = run;
      run += blkhist[b * NT + tid];
    }
  }
}

// Rank within block via LDS atomic; placement is exact (no global atomics).
__global__ __launch_bounds__(256) void trix_scatter(const int* __restrict__ tidx,
                                                    const int* __restrict__ blkbase,
                                                    int* __restrict__ rowlist) {
  __shared__ int h[NT];
  int tid = threadIdx.x;
  if (tid < NT) h[tid] = 0;
  __syncthreads();
  int row = blockIdx.x * 256 + tid;
  int t = tidx[row];
  int r = atomicAdd(&h[t], 1);
  rowlist[blkbase[blockIdx.x * NT + t] + r] = row;
}

// W f32 [16][1000][1024] -> bf16 [16][1024][1024], cols 1000..1023 zeroed.
__global__ __launch_bounds__(256) void w_conv(const float* __restrict__ W,
                                              ushort_t* __restrict__ wbf) {
  size_t e = ((size_t)blockIdx.x * 256 + threadIdx.x) * 8;
  int t = (int)(e >> 20);
  int rem = (int)(e & 1048575);
  int col = rem >> 10, k = rem & 1023;
  uint4 o;
  if (col < NC) {
    const float* src = W + ((size_t)t * NC + col) * ND + k;
    float4 a = *(const float4*)src;
    float4 b = *(const float4*)(src + 4);
    o = make_uint4(pk2(a.x, a.y), pk2(a.z, a.w), pk2(b.x, b.y), pk2(b.z, b.w));
  } else {
    o = make_uint4(0, 0, 0, 0);
  }
  *(uint4*)(wbf + e) = o;
}

// m97-structure GEMM: linear LDS [128][32] bf16, global_load_lds width-16,
// 8 ds_read_b128 + 16 MFMA per k-step, 2 barriers.
__global__ __launch_bounds__(256) void trix_gemm_bf16(
    const ushort_t* __restrict__ xbf, const ushort_t* __restrict__ wbf,
    const float* __restrict__ bias, const int* __restrict__ meta,
    const int* __restrict__ rowlist, float* __restrict__ out) {
  __shared__ __align__(16) ushort_t A_lds[BM * 32];
  __shared__ __align__(16) ushort_t B_lds[BN * 32];
  __shared__ int rl[BM];
  int nb = blockIdx.x, rb = blockIdx.y;
  if (rb >= meta[49]) return;
  int t = 0;
  while (t < NT - 1 && rb >= meta[34 + t]) t++;
  int row0 = meta[16 + t] + (rb - meta[33 + t]) * BM;
  int cnt = meta[17 + t] - row0;
  if (cnt > BM) cnt = BM;
  int tid = threadIdx.x;
  if (tid < BM) rl[tid] = rowlist[(tid < cnt) ? (row0 + tid) : row0];
  __syncthreads();

  int cr = tid >> 2, cq = tid & 3;
  const ushort_t* ga0 = xbf + (size_t)rl[cr] * ND + cq * 8;
  const ushort_t* ga1 = xbf + (size_t)rl[64 + cr] * ND + cq * 8;
  const ushort_t* gb0 = wbf + ((size_t)t << 20) + (size_t)(nb * BN + cr) * ND + cq * 8;
  const ushort_t* gb1 = wbf + ((size_t)t << 20) + (size_t)(nb * BN + 64 + cr) * ND + cq * 8;
  ushort_t* la0 = A_lds + tid * 8;
  ushort_t* la1 = A_lds + 2048 + tid * 8;
  ushort_t* lb0 = B_lds + tid * 8;
  ushort_t* lb1 = B_lds + 2048 + tid * 8;

  int lane = tid & 63, wv = tid >> 6;
  int wr = wv >> 1, wc = wv & 1;
  int rsel = lane & 15, slot = lane >> 4;
  f32x4 acc[4][4] = {};

  for (int k0 = 0; k0 < ND; k0 += 32) {
    async_copy16(ga0 + k0, la0);
    async_copy16(ga1 + k0, la1);
    async_copy16(gb0 + k0, lb0);
    async_copy16(gb1 + k0, lb1);
    __syncthreads();
    short8 af[4], bfr[4];
#pragma unroll
    for (int i = 0; i < 4; i++) {
      af[i] = *(const short8*)(A_lds + (wr * 64 + i * 16 + rsel) * 32 + slot * 8);
      bfr[i] = *(const short8*)(B_lds + (wc * 64 + i * 16 + rsel) * 32 + slot * 8);
    }
#pragma unroll
    for (int mi = 0; mi < 4; mi++)
#pragma unroll
      for (int ni = 0; ni < 4; ni++)
        acc[mi][ni] = __builtin_amdgcn_mfma_f32_16x16x32_bf16(af[mi], bfr[ni], acc[mi][ni], 0, 0, 0);
    __syncthreads();
  }

#pragma unroll
  for (int mi = 0; mi < 4; mi++) {
#pragma unroll
    for (int r = 0; r < 4; r++) {
      int rloc2 = wr * 64 + mi * 16 + slot * 4 + r;  // C/D: col=lane&15, row=(lane>>4)*4+reg
      if (rloc2 < cnt) {
        size_t obase = (size_t)rl[rloc2] * NC;
#pragma unroll
        for (int ni = 0; ni < 4; ni++) {
          int col = nb * BN + wc * 64 + ni * 16 + rsel;
          if (col < NC) out[obase + col] = acc[mi][ni][r] + bias[t * NC + col];
        }
      }
    }
  }
}

// Fallback GEMM (f32 inputs, in-loop repack) if ws is too small for bf16 staging.
__global__ __launch_bounds__(256) void trix_gemm_fb(
    const float* __restrict__ x, const float* __restrict__ W,
    const float* __restrict__ bias, const int* __restrict__ meta,
    const int* __restrict__ rowlist, float* __restrict__ out) {
  __shared__ __align__(16) unsigned char aT[BM * 64];
  __shared__ __align__(16) unsigned char bT[BN * 64];
  __shared__ int rl[BM];
  int nb = blockIdx.x, rb = blockIdx.y;
  if (rb >= meta[49]) return;
  int t = 0;
  while (t < NT - 1 && rb >= meta[34 + t]) t++;
  int row0 = meta[16 + t] + (rb - meta[33 + t]) * BM;
  int cnt = meta[17 + t] - row0;
  if (cnt > BM) cnt = BM;
  int tid = threadIdx.x;
  if (tid < BM) rl[tid] = rowlist[(tid < cnt) ? (row0 + tid) : row0];
  __syncthreads();
  int half = tid & 1, rloc = tid >> 1;
  const float* xp = x + (size_t)rl[rloc] * ND + half * 16;
  int wn = nb * BN + rloc;
  if (wn > NC - 1) wn = NC - 1;
  const float* wp = W + ((size_t)t * NC + wn) * ND + half * 16;
  int sw = swz(rloc);
  unsigned char* aw0 = aT + rloc * 64 + (((half * 2 + 0) ^ sw) << 4);
  unsigned char* aw1 = aT + rloc * 64 + (((half * 2 + 1) ^ sw) << 4);
  unsigned char* bw0 = bT + rloc * 64 + (((half * 2 + 0) ^ sw) << 4);
  unsigned char* bw1 = bT + rloc * 64 + (((half * 2 + 1) ^ sw) << 4);
  int lane = tid & 63, wv = tid >> 6;
  int wr = wv >> 1, wc = wv & 1;
  int rsel = lane & 15, slot = lane >> 4;
  f32x4 acc[4][4] = {};
  for (int k0 = 0; k0 < ND; k0 += 32) {
    const float* xk = xp + k0;
    const float* wk = wp + k0;
    float4 a0 = *(const float4*)(xk);
    float4 a1 = *(const float4*)(xk + 4);
    float4 a2 = *(const float4*)(xk + 8);
    float4 a3 = *(const float4*)(xk + 12);
    float4 b0 = *(const float4*)(wk);
    float4 b1 = *(const float4*)(wk + 4);
    float4 b2 = *(const float4*)(wk + 8);
    float4 b3 = *(const float4*)(wk + 12);
    *(uint4*)aw0 = make_uint4(pk2(a0.x, a0.y), pk2(a0.z, a0.w), pk2(a1.x, a1.y), pk2(a1.z, a1.w));
    *(uint4*)aw1 = make_uint4(pk2(a2.x, a2.y), pk2(a2.z, a2.w), pk2(a3.x, a3.y), pk2(a3.z, a3.w));
    *(uint4*)bw0 = make_uint4(pk2(b0.x, b0.y), pk2(b0.z, b0.w), pk2(b1.x, b1.y), pk2(b1.z, b1.w));
    *(uint4*)bw1 = make_uint4(pk2(b2.x, b2.y), pk2(b2.z, b2.w), pk2(b3.x, b3.y), pk2(b3.z, b3.w));
    __syncthreads();
    short8 af[4], bfr[4];
#pragma unroll
    for (int i = 0; i < 4; i++) {
      int ar = wr * 64 + i * 16 + rsel;
      af[i] = *(const short8*)(aT + ar * 64 + ((slot ^ swz(ar)) << 4));
      int br = wc * 64 + i * 16 + rsel;
      bfr[i] = *(const short8*)(bT + br * 64 + ((slot ^ swz(br)) << 4));
    }
#pragma unroll
    for (int mi = 0; mi < 4; mi++)
#pragma unroll
      for (int ni = 0; ni < 4; ni++)
        acc[mi][ni] = __builtin_amdgcn_mfma_f32_16x16x32_bf16(af[mi], bfr[ni], acc[mi][ni], 0, 0, 0);
    __syncthreads();
  }
#pragma unroll
  for (int mi = 0; mi < 4; mi++) {
#pragma unroll
    for (int r = 0; r < 4; r++) {
      int rloc2 = wr * 64 + mi * 16 + slot * 4 + r;
      if (rloc2 < cnt) {
        size_t obase = (size_t)rl[rloc2] * NC;
#pragma unroll
        for (int ni = 0; ni < 4; ni++) {
          int col = nb * BN + wc * 64 + ni * 16 + rsel;
          if (col < NC) out[obase + col] = acc[mi][ni][r] + bias[t * NC + col];
        }
      }
    }
  }
}

extern "C" void kernel_launch(void* const* d_in, const int* in_sizes, int n_in,
                              void* d_out, int out_size, void* d_ws, size_t ws_size,
                              hipStream_t stream) {
  const float* x = (const float*)d_in[0];
  const float* sigs = (const float*)d_in[1];
  const float* W = (const float*)d_in[2];
  const float* bias = (const float*)d_in[3];
  float* out = (float*)d_out;

  const size_t XBF = (size_t)NBROWS * ND * 2;     // 67,108,864
  const size_t WBF = (size_t)NT * 1024 * ND * 2;  // 33,554,432
  bool fast = ws_size >= XBF + WBF + (1 << 20);

  char* wsb = (char*)d_ws;
  ushort_t* xbf = nullptr;
  ushort_t* wbf = nullptr;
  int* tidx;
  if (fast) {
    xbf = (ushort_t*)wsb;
    wbf = (ushort_t*)(wsb + XBF);
    tidx = (int*)(wsb + XBF + WBF);
  } else {
    tidx = (int*)wsb;
  }
  int* rowlist = tidx + NBROWS;
  int* meta = rowlist + NBROWS;
  int* blkhist = meta + 66;
  int* blkbase = blkhist + NHB * NT;

  trix_scores<<<NBROWS / 8, 512, 0, stream>>>(x, sigs, tidx, out + (size_t)NBROWS * NC, xbf);
  trix_hist<<<NHB, 256, 0, stream>>>(tidx, blkhist);
  trix_prefix<<<1, 256, 0, stream>>>(blkhist, blkbase, meta);
  trix_scatter<<<NHB, 256, 0, stream>>>(tidx, blkbase, rowlist);
  if (fast) {
    w_conv<<<(NT * 1024 * ND / 8) / 256, 256, 0, stream>>>(W, wbf);
    trix_gemm_bf16<<<dim3(NBN, MAX_RB), 256, 0, stream>>>(xbf, wbf, bias, meta, rowlist, out);
  } else {
    trix_gemm_fb<<<dim3(NBN, MAX_RB), 256, 0, stream>>>(x, W, bias, meta, rowlist, out);
  }
}